// Round 12
// baseline (434.405 us; speedup 1.0000x reference)
//
#include <hip/hip_runtime.h>

// MeshConv R10 (3rd submit; two broker timeouts): out = combined @ W.T + b.
//
// R9 learning: occupancy lever DEAD (clean run, +45% occupancy, dur unchanged
// at ~160us / 3.5 TB/s) -> service-rate-limited on the 54%-random mix, not
// concurrency-limited. Remaining gap is BYTES: ~168MB of gather re-fetch
// because the 128MB f32 x image loses ~1/3 of its lines to the 250MB nt
// out-stream in the 256MB L3.
//
// R10 = clean retest of the fp16-staged image. R5's refutation was
// CONTAMINATED: its main kernel had VGPR 40 (spill traffic hammering L3) and
// the broken 64B-store epilogue (478MB writes churning L3). Both fixed since.
// A 64MB fp16 image has 4x the L3 headroom of the f32 image; if resident,
// gathers become L3 hits and main-kernel HBM traffic ~= streams only.
//  - structure = R9 skeleton exactly (proven: VGPR 72, byte-exact, no spills):
//    single gather buffer, 4-phase fenced epilogue, plain launch_bounds(256).
//  - fp16 halves cb (40->20 VGPR): live set ~60, far from any cliff.
// SENTINELS: main VGPR >52 & WRITE == 250,000 KiB (else spill-poisoned);
//            main FETCH <=130MB -> theory confirmed (~80-110us main);
//            main FETCH >=250MB -> fp16 path definitively dead -> roofline.
// Fallback: ws too small -> R9 f32 kernel verbatim (proven 160us).

typedef __bf16    bf16_t;
typedef __bf16    bf16x8 __attribute__((ext_vector_type(8)));
typedef _Float16  f16_t;
typedef _Float16  f16x8  __attribute__((ext_vector_type(8)));
typedef float     f32x4  __attribute__((ext_vector_type(4)));

#define EC        1000000
#define CCH       32
#define OUTD      64
#define KD        160          // 5*CCH
#define MT        64           // elements per tile
#define NTILES    (EC / MT)    // 15625
#define NFRAG     1280         // 5 ks * 4 tn * 4 quad * 16 col frags of 8 bf16
#define TSTR      68           // epilogue LDS row stride (floats)
#define GRID_F16  1536         // 6 blocks/CU if LDS-limited occupancy lands
#define GRID_F32  1280
#define CVT_GRID  2048

// ---------------------------------------------------------------------------
// staging: x f32 -> f16 image in workspace. nt loads keep the dead f32 copy
// out of L3; normal stores prime L3 with the image the gathers will hit.
// ---------------------------------------------------------------------------
__global__ __launch_bounds__(256)
void cvt_x_f16(const float* __restrict__ x, f16_t* __restrict__ xh)
{
    const size_t n8     = (size_t)EC * CCH / 8;     // 4,000,000 groups of 8
    const size_t stride = (size_t)CVT_GRID * 256;
    size_t i = (size_t)blockIdx.x * 256 + threadIdx.x;
    for (; i < n8; i += stride) {
        const f32x4* p = (const f32x4*)x + 2 * i;
        f32x4 a = __builtin_nontemporal_load(p);
        f32x4 b = __builtin_nontemporal_load(p + 1);
        f16x8 h;
        h[0]=(f16_t)a[0]; h[1]=(f16_t)a[1]; h[2]=(f16_t)a[2]; h[3]=(f16_t)a[3];
        h[4]=(f16_t)b[0]; h[5]=(f16_t)b[1]; h[6]=(f16_t)b[2]; h[7]=(f16_t)b[3];
        *((f16x8*)xh + i) = h;
    }
}

// ---------------------------------------------------------------------------
// main fp16-gather kernel: R9 skeleton (single buffer, fenced 4-phase
// epilogue, no min-waves attribute), fp16 rows (64B, one 16B load per lane).
// ---------------------------------------------------------------------------
__global__ __launch_bounds__(256)
void meshconv_f16(const f16_t* __restrict__ xh,
                  const int*   __restrict__ nbr,
                  const float* __restrict__ W,
                  const float* __restrict__ bias,
                  float*       __restrict__ out)
{
    __shared__ bf16_t w_lds[NFRAG * 8];                                // 20.0 KB
    __shared__ __attribute__((aligned(16))) float t_lds[4 * 4 * TSTR]; // 4.25 KB

    const int tid  = threadIdx.x;
    const int wave = tid >> 6;
    const int lane = tid & 63;
    const int col  = lane & 15;
    const int quad = lane >> 4;

    // ---- one-time: W (64x160 f32) -> bf16 LDS, frag-swizzled ----
    // frag(ks,tn,quad,col,j) = W[o = tn*16+col][k = ks*32 + quad*8 + j]
    for (int i = tid; i < NFRAG; i += 256) {
        const int fc  = i & 15;
        const int fq  = (i >> 4) & 3;
        const int ftn = (i >> 6) & 3;
        const int fks = i >> 8;
        const float* src = W + (ftn * 16 + fc) * KD + fks * 32 + fq * 8;
        f32x4 w0 = *(const f32x4*)src;
        f32x4 w1 = *(const f32x4*)(src + 4);
        bf16x8 wf;
        wf[0]=(bf16_t)w0[0]; wf[1]=(bf16_t)w0[1]; wf[2]=(bf16_t)w0[2]; wf[3]=(bf16_t)w0[3];
        wf[4]=(bf16_t)w1[0]; wf[5]=(bf16_t)w1[1]; wf[6]=(bf16_t)w1[2]; wf[7]=(bf16_t)w1[3];
        *(bf16x8*)&w_lds[i * 8] = wf;
    }

    float bv[4];
#pragma unroll
    for (int tn = 0; tn < 4; ++tn) bv[tn] = bias[tn * 16 + col];

    float* tw = &t_lds[wave * 4 * TSTR];   // per-wave 4-row region

    __syncthreads();   // w_lds ready; read-only hereafter

    auto ld_nbr = [&](int t) -> int4 {
        return ((const int4*)nbr)[t * MT + wave * 16 + col];
    };
    // 5 rows x 8 channels (this lane's quad slice): one 16B load per row;
    // 4 quads of a col cover the row's full 64B.
    auto gather = [&](int t, const int4& nb, f16x8* buf) {
        const int e  = t * MT + wave * 16 + col;
        const int i0 = nb.x < 0 ? 0 : nb.x;
        const int i1 = nb.y < 0 ? 0 : nb.y;
        const int i2 = nb.z < 0 ? 0 : nb.z;
        const int i3 = nb.w < 0 ? 0 : nb.w;
        const int co = quad * 8;
        buf[0] = *(const f16x8*)(xh + (size_t)e  * CCH + co);
        buf[1] = *(const f16x8*)(xh + (size_t)i0 * CCH + co);
        buf[2] = *(const f16x8*)(xh + (size_t)i1 * CCH + co);
        buf[3] = *(const f16x8*)(xh + (size_t)i2 * CCH + co);
        buf[4] = *(const f16x8*)(xh + (size_t)i3 * CCH + co);
    };

    int tile = blockIdx.x;
    int4  nb_cur, nb_nxt;
    f16x8 cb[5];
    if (tile < NTILES) {
        nb_cur = ld_nbr(tile);                  // prologue: serial once
        gather(tile, nb_cur, cb);
        const int t1 = (tile + GRID_F16 < NTILES) ? tile + GRID_F16 : tile;
        nb_nxt = ld_nbr(t1);
    }

    for (; tile < NTILES; tile += GRID_F16) {
        // ---- descriptor slices == the 5 A-frags; cb fully consumed here ----
        const float m0 = nb_cur.x < 0 ? 0.f : 1.f;
        const float m1 = nb_cur.y < 0 ? 0.f : 1.f;
        const float m2 = nb_cur.z < 0 ? 0.f : 1.f;
        const float m3 = nb_cur.w < 0 ? 0.f : 1.f;

        bf16x8 af[5];
#pragma unroll
        for (int jj = 0; jj < 8; ++jj) {
            const float va0 = (float)cb[1][jj] * m0;
            const float va1 = (float)cb[2][jj] * m1;
            const float vb0 = (float)cb[3][jj] * m2;
            const float vb1 = (float)cb[4][jj] * m3;
            const float sa = va0 + va1;
            const float da = fabsf(va0 - va1);
            const float sb = vb0 + vb1;
            const float db = fabsf(vb0 - vb1);
            af[0][jj] = (bf16_t)(float)cb[0][jj];
            af[1][jj] = (bf16_t)(sa + sb);
            af[2][jj] = (bf16_t)(da + db);
            af[3][jj] = (bf16_t)fabsf(sa - sb);
            af[4][jj] = (bf16_t)fabsf(da - db);
        }

        // ---- cb is dead: issue next tile's gather into it NOW (in flight
        //      through MFMA + epilogue) ----
        const int nxt = tile + GRID_F16;
        int4 nb2 = nb_nxt;
        if (nxt < NTILES) {
            gather(nxt, nb_nxt, cb);
            const int t2 = (nxt + GRID_F16 < NTILES) ? nxt + GRID_F16 : nxt;
            nb2 = ld_nbr(t2);                   // nbr two tiles ahead
        }

        // ---- MFMA: acc[tn][r] = C(e-row = quad*4+r, o = tn*16+col) ----
        f32x4 acc[4] = {{0.f,0.f,0.f,0.f},{0.f,0.f,0.f,0.f},
                        {0.f,0.f,0.f,0.f},{0.f,0.f,0.f,0.f}};
#pragma unroll
        for (int ks = 0; ks < 5; ++ks) {
#pragma unroll
            for (int tn = 0; tn < 4; ++tn) {
                const bf16x8 bfr = *(const bf16x8*)&w_lds[(((ks*4+tn)*4+quad)*16 + col) * 8];
                acc[tn] = __builtin_amdgcn_mfma_f32_16x16x32_bf16(af[ks], bfr, acc[tn], 0, 0, 0);
            }
        }

        // ---- epilogue: 4-phase in-wave LDS transpose -> full-line nt stores.
        // asm fences stop GVN from CSE'ing the identical-address reads
        // (R4's bug, fixed+proven R5/R9). HW DS ops are in-order per wave.
        // Each nt store instruction covers 4 rows x 256B = 1KB contiguous.
#pragma unroll
        for (int p = 0; p < 4; ++p) {
            if (quad == p) {
#pragma unroll
                for (int tn = 0; tn < 4; ++tn)
#pragma unroll
                    for (int r = 0; r < 4; ++r)
                        tw[r * TSTR + tn * 16 + col] = acc[tn][r] + bv[tn];
            }
            asm volatile("" ::: "memory");   // stores above visible; no load CSE
            const f32x4 v = *(const f32x4*)&tw[quad * TSTR + col * 4];
            asm volatile("" ::: "memory");   // read done before next phase's writes
            float* op = out + (size_t)(tile * MT + wave * 16 + p * 4 + quad) * OUTD + col * 4;
            __builtin_nontemporal_store(v, (f32x4*)op);
        }

        // ---- rotate nbr pipeline (gather buffer already rotated in-place) ----
        nb_cur = nb_nxt;
        nb_nxt = nb2;
    }
}

// ---------------------------------------------------------------------------
// R9 f32 fallback (proven: VGPR 72, byte-exact, 160us). Used only if the
// workspace cannot hold the 64MB fp16 image.
// ---------------------------------------------------------------------------
__global__ __launch_bounds__(256)
void meshconv_kernel(const float* __restrict__ x,
                     const int*   __restrict__ nbr,
                     const float* __restrict__ W,
                     const float* __restrict__ bias,
                     float*       __restrict__ out)
{
    __shared__ bf16_t w_lds[NFRAG * 8];
    __shared__ __attribute__((aligned(16))) float t_lds[4 * 4 * TSTR];

    const int tid  = threadIdx.x;
    const int wave = tid >> 6;
    const int lane = tid & 63;
    const int col  = lane & 15;
    const int quad = lane >> 4;

    for (int i = tid; i < NFRAG; i += 256) {
        const int fc  = i & 15;
        const int fq  = (i >> 4) & 3;
        const int ftn = (i >> 6) & 3;
        const int fks = i >> 8;
        const float* src = W + (ftn * 16 + fc) * KD + fks * 32 + fq * 8;
        f32x4 w0 = *(const f32x4*)src;
        f32x4 w1 = *(const f32x4*)(src + 4);
        bf16x8 wf;
        wf[0]=(bf16_t)w0[0]; wf[1]=(bf16_t)w0[1]; wf[2]=(bf16_t)w0[2]; wf[3]=(bf16_t)w0[3];
        wf[4]=(bf16_t)w1[0]; wf[5]=(bf16_t)w1[1]; wf[6]=(bf16_t)w1[2]; wf[7]=(bf16_t)w1[3];
        *(bf16x8*)&w_lds[i * 8] = wf;
    }

    float bv[4];
#pragma unroll
    for (int tn = 0; tn < 4; ++tn) bv[tn] = bias[tn * 16 + col];

    float* tw = &t_lds[wave * 4 * TSTR];

    __syncthreads();

    auto ld_nbr = [&](int t) -> int4 {
        return ((const int4*)nbr)[t * MT + wave * 16 + col];
    };
    auto gather = [&](int t, const int4& nb, f32x4* buf) {
        const int e  = t * MT + wave * 16 + col;
        const int i0 = nb.x < 0 ? 0 : nb.x;
        const int i1 = nb.y < 0 ? 0 : nb.y;
        const int i2 = nb.z < 0 ? 0 : nb.z;
        const int i3 = nb.w < 0 ? 0 : nb.w;
        const int co = quad * 8;
        const f32x4* p;
        p = (const f32x4*)(x + (size_t)e  * CCH + co); buf[0] = p[0]; buf[1] = p[1];
        p = (const f32x4*)(x + (size_t)i0 * CCH + co); buf[2] = p[0]; buf[3] = p[1];
        p = (const f32x4*)(x + (size_t)i1 * CCH + co); buf[4] = p[0]; buf[5] = p[1];
        p = (const f32x4*)(x + (size_t)i2 * CCH + co); buf[6] = p[0]; buf[7] = p[1];
        p = (const f32x4*)(x + (size_t)i3 * CCH + co); buf[8] = p[0]; buf[9] = p[1];
    };

    int tile = blockIdx.x;
    int4  nb_cur, nb_nxt;
    f32x4 cb[10];
    if (tile < NTILES) {
        nb_cur = ld_nbr(tile);
        gather(tile, nb_cur, cb);
        const int t1 = (tile + GRID_F32 < NTILES) ? tile + GRID_F32 : tile;
        nb_nxt = ld_nbr(t1);
    }

    for (; tile < NTILES; tile += GRID_F32) {
        const float m0 = nb_cur.x < 0 ? 0.f : 1.f;
        const float m1 = nb_cur.y < 0 ? 0.f : 1.f;
        const float m2 = nb_cur.z < 0 ? 0.f : 1.f;
        const float m3 = nb_cur.w < 0 ? 0.f : 1.f;

        bf16x8 af[5];
#pragma unroll
        for (int h = 0; h < 2; ++h) {
#pragma unroll
            for (int j = 0; j < 4; ++j) {
                const int jj = h * 4 + j;
                const float va0 = cb[2 + h][j] * m0;
                const float va1 = cb[4 + h][j] * m1;
                const float vb0 = cb[6 + h][j] * m2;
                const float vb1 = cb[8 + h][j] * m3;
                const float sa = va0 + va1;
                const float da = fabsf(va0 - va1);
                const float sb = vb0 + vb1;
                const float db = fabsf(vb0 - vb1);
                af[0][jj] = (bf16_t)cb[h][j];
                af[1][jj] = (bf16_t)(sa + sb);
                af[2][jj] = (bf16_t)(da + db);
                af[3][jj] = (bf16_t)fabsf(sa - sb);
                af[4][jj] = (bf16_t)fabsf(da - db);
            }
        }

        const int nxt = tile + GRID_F32;
        int4 nb2 = nb_nxt;
        if (nxt < NTILES) {
            gather(nxt, nb_nxt, cb);
            const int t2 = (nxt + GRID_F32 < NTILES) ? nxt + GRID_F32 : nxt;
            nb2 = ld_nbr(t2);
        }

        f32x4 acc[4] = {{0.f,0.f,0.f,0.f},{0.f,0.f,0.f,0.f},
                        {0.f,0.f,0.f,0.f},{0.f,0.f,0.f,0.f}};
#pragma unroll
        for (int ks = 0; ks < 5; ++ks) {
#pragma unroll
            for (int tn = 0; tn < 4; ++tn) {
                const bf16x8 bfr = *(const bf16x8*)&w_lds[(((ks*4+tn)*4+quad)*16 + col) * 8];
                acc[tn] = __builtin_amdgcn_mfma_f32_16x16x32_bf16(af[ks], bfr, acc[tn], 0, 0, 0);
            }
        }

#pragma unroll
        for (int p = 0; p < 4; ++p) {
            if (quad == p) {
#pragma unroll
                for (int tn = 0; tn < 4; ++tn)
#pragma unroll
                    for (int r = 0; r < 4; ++r)
                        tw[r * TSTR + tn * 16 + col] = acc[tn][r] + bv[tn];
            }
            asm volatile("" ::: "memory");
            const f32x4 v = *(const f32x4*)&tw[quad * TSTR + col * 4];
            asm volatile("" ::: "memory");
            float* op = out + (size_t)(tile * MT + wave * 16 + p * 4 + quad) * OUTD + col * 4;
            __builtin_nontemporal_store(v, (f32x4*)op);
        }

        nb_cur = nb_nxt;
        nb_nxt = nb2;
    }
}

extern "C" void kernel_launch(void* const* d_in, const int* in_sizes, int n_in,
                              void* d_out, int out_size, void* d_ws, size_t ws_size,
                              hipStream_t stream) {
    const float* x    = (const float*)d_in[0];
    const int*   nbr  = (const int*)d_in[1];
    const float* W    = (const float*)d_in[2];
    const float* bias = (const float*)d_in[3];
    float* out = (float*)d_out;

    const size_t need = (size_t)EC * CCH * sizeof(f16_t);   // 64 MB fp16 image
    if (d_ws != nullptr && ws_size >= need) {
        f16_t* xh = (f16_t*)d_ws;
        cvt_x_f16<<<dim3(CVT_GRID), dim3(256), 0, stream>>>(x, xh);
        meshconv_f16<<<dim3(GRID_F16), dim3(256), 0, stream>>>(xh, nbr, W, bias, out);
    } else {
        meshconv_kernel<<<dim3(GRID_F32), dim3(256), 0, stream>>>(x, nbr, W, bias, out);
    }
}